// Round 1
// baseline (324.713 us; speedup 1.0000x reference)
//
#include <hip/hip_runtime.h>
#include <hip/hip_bf16.h>
#include <math.h>

typedef short short8 __attribute__((ext_vector_type(8)));
typedef float f32x4 __attribute__((ext_vector_type(4)));

// ---- problem dims (fixed by setup_inputs) ----
#define BTN   128            // b*t
#define HWN   196            // 14*14
#define CCH   1024
#define NPIX  (BTN * HWN)    // 25088 = 196 * 128
#define BTSTR (CCH * HWN)    // 200704 floats per bt slab

// ---- workspace layout (bytes) ----
#define WS_D  0                      // d matrix bf16 [NPIX][1024]  = 51,380,224 B
#define WS_BW 51380224               // conv_w bf16 [1024][1024]    =  2,097,152 B
#define WS_TW 53477376               // twiddles: tw512[256] + tw1024[257] float2

__device__ __forceinline__ float2 cmulf(float2 a, float2 b) {
  return make_float2(a.x * b.x - a.y * b.y, a.x * b.y + a.y * b.x);
}
__device__ __forceinline__ unsigned short f2bf(float f) {   // RNE fp32->bf16
  unsigned u = __float_as_uint(f);
  unsigned r = (u + 0x7fffu + ((u >> 16) & 1u)) >> 16;
  return (unsigned short)r;
}

// ---------------------------------------------------------------- twiddles
__global__ void init_tw_kernel(float2* __restrict__ tw) {
  int i = threadIdx.x;
  if (i < 256) {  // W_512^k = e^{-2pi i k/512}
    double a = -6.283185307179586232 * (double)i / 512.0;
    tw[i] = make_float2((float)cos(a), (float)sin(a));
  }
  if (i < 257) {  // W_1024^f
    double a = -6.283185307179586232 * (double)i / 1024.0;
    tw[256 + i] = make_float2((float)cos(a), (float)sin(a));
  }
}

// ---------------------------------------------------------------- W -> bf16
__global__ void wcast_kernel(const float* __restrict__ w, unsigned short* __restrict__ o) {
  int i = (blockIdx.x * 256 + threadIdx.x) * 4;   // grid 1024 x 256 covers 1<<20
  float4 v = *(const float4*)(w + i);
  uint2 u;
  u.x = (unsigned)f2bf(v.x) | ((unsigned)f2bf(v.y) << 16);
  u.y = (unsigned)f2bf(v.z) | ((unsigned)f2bf(v.w) << 16);
  *(uint2*)(o + i) = u;
}

// ---------------------------------------------------------------- stage 1: FFT filter
// One pixel per wave, 4 waves/block. 512-pt half-complex FFT:
//   z[j] = x[2j] + i x[2j+1]; DIF forward (natural->bitrev);
//   unpack to X[f], f=0..512; Y = X * wc * (1/512) (Im of bins 0,512 dropped,
//   matching numpy irfft); repack Z'[f] at bitrev(f); DIT inverse (bitrev->natural).
__global__ __launch_bounds__(256) void fft_filter_kernel(
    const float* __restrict__ x, const float* __restrict__ wfilt,
    const float2* __restrict__ twg, unsigned short* __restrict__ dmat) {
  __shared__ float2 Z[4][512];
  __shared__ float2 tw5[256];    // W_512^k
  __shared__ float2 tw10[257];   // W_1024^f
  int tid = threadIdx.x;
  int l = tid & 63, w = tid >> 6;
  tw5[tid & 255] = twg[tid & 255];
  tw10[tid & 255] = twg[256 + (tid & 255)];
  if (tid == 0) tw10[256] = twg[512];

  // block -> (bt, hw): keep all pixels of one bt (and one t) on one XCD for L2 reuse
  int bid = blockIdx.x;                 // 6272 blocks = 8 * 784
  int X = bid & 7, slot = bid >> 3;     // slot in [0,784)
  int bt = (slot / 49) * 8 + X;         // t = bt & 7 == X
  int hw = (slot % 49) * 4 + w;
  const float* xp = x + (size_t)bt * BTSTR + hw;   // channel stride = 196 floats
  float2* z = Z[w];
  __syncthreads();

  // load: z[j] = x[2j] + i x[2j+1]
#pragma unroll
  for (int i = 0; i < 8; ++i) {
    int j = l + 64 * i;
    z[j] = make_float2(xp[(2 * j) * HWN], xp[(2 * j + 1) * HWN]);
  }
  __syncthreads();

  // forward DIF, 9 stages
  for (int st = 0; st < 9; ++st) {
    int half = 256 >> st;
#pragma unroll
    for (int qi = 0; qi < 4; ++qi) {
      int q = l + 64 * qi;
      int j = q & (half - 1);
      int base = (q >> (8 - st)) << (9 - st);
      float2 a = z[base + j], b = z[base + j + half];
      float2 t = tw5[j << st];
      float2 dd = make_float2(a.x - b.x, a.y - b.y);
      z[base + j] = make_float2(a.x + b.x, a.y + b.y);
      z[base + j + half] = cmulf(dd, t);
    }
    __syncthreads();
  }

  // middle: unpack real spectrum, filter, repack (positions are bitrev(f))
  {
    const float* wf = wfilt + (size_t)((bt & 7) * HWN + hw) * 1026;  // [513][2]
    const float sc = 1.0f / 512.0f;
#pragma unroll
    for (int i = 0; i < 4; ++i) {
      int f = 64 * i + l;
      if (f == 0) {
        float2 z0 = z[0];                       // Z[0]
        float X0 = z0.x + z0.y, X512 = z0.x - z0.y;
        float Y0 = X0 * wf[0] * sc;             // irfft ignores Im at bin 0
        float Y512 = X512 * wf[1024] * sc;      // and bin 512
        z[0] = make_float2(0.5f * (Y0 + Y512), 0.5f * (Y0 - Y512));
        float2 z2 = z[1];                       // bitrev(256)=1 -> Z[256]
        float2 X256 = make_float2(z2.x, -z2.y); // conj(Z256)
        float2 Y = cmulf(X256, make_float2(wf[512], wf[513]));
        z[1] = make_float2(Y.x * sc, -Y.y * sc);
      } else {
        int g = 512 - f;
        int pf = (int)(__brev((unsigned)f) >> 23);
        int pg = (int)(__brev((unsigned)g) >> 23);
        float2 Zf = z[pf], Zg = z[pg];
        float2 A = make_float2(0.5f * (Zf.x + Zg.x), 0.5f * (Zf.y - Zg.y));
        float2 B = make_float2(0.5f * (Zf.y + Zg.y), -0.5f * (Zf.x - Zg.x));
        float2 Wf = tw10[f];
        float2 WB = cmulf(Wf, B);
        float2 Xf = make_float2(A.x + WB.x, A.y + WB.y);       // X[f]
        float2 Xg = make_float2(A.x - WB.x, -(A.y - WB.y));    // X[512-f] = conj(A-WB)
        float2 Yf = cmulf(Xf, make_float2(wf[2 * f], wf[2 * f + 1]));
        float2 Yg = cmulf(Xg, make_float2(wf[2 * g], wf[2 * g + 1]));
        Yf.x *= sc; Yf.y *= sc; Yg.x *= sc; Yg.y *= sc;
        float2 Ap = make_float2(0.5f * (Yf.x + Yg.x), 0.5f * (Yf.y - Yg.y));
        float2 T  = make_float2(0.5f * (Yf.x - Yg.x), 0.5f * (Yf.y + Yg.y));
        float2 Bp = cmulf(make_float2(Wf.x, -Wf.y), T);
        z[pf] = make_float2(Ap.x - Bp.y, Ap.y + Bp.x);         // Z'[f] = A' + iB'
        z[pg] = make_float2(Ap.x + Bp.y, Bp.x - Ap.y);         // Z'[g] = conj(A'-iB')
      }
    }
  }
  __syncthreads();

  // inverse DIT, 9 stages (conj twiddles; the 1/512 was folded into sc)
  for (int st = 8; st >= 0; --st) {
    int half = 256 >> st;
#pragma unroll
    for (int qi = 0; qi < 4; ++qi) {
      int q = l + 64 * qi;
      int j = q & (half - 1);
      int base = (q >> (8 - st)) << (9 - st);
      float2 a = z[base + j], b = z[base + j + half];
      float2 t = tw5[j << st];
      float2 bw = make_float2(b.x * t.x + b.y * t.y, b.y * t.x - b.x * t.y); // b*conj(t)
      z[base + j] = make_float2(a.x + bw.x, a.y + bw.y);
      z[base + j + half] = make_float2(a.x - bw.x, a.y - bw.y);
    }
    __syncthreads();
  }

  // write d row (bf16): d[2j]=Re z[j], d[2j+1]=Im z[j]
  unsigned short* drow = dmat + (size_t)(bt * HWN + hw) * CCH;
#pragma unroll
  for (int i = 0; i < 8; ++i) {
    int j = l + 64 * i;
    float2 v = z[j];
    unsigned u = (unsigned)f2bf(v.x) | ((unsigned)f2bf(v.y) << 16);
    *(unsigned*)(drow + 2 * j) = u;
  }
}

// ---------------------------------------------------------------- stage 2: GEMM + GELU + residual
// e[p][o] = sum_c d[p][c] * W[o][c] + b[o]; out = x + gelu(e)
// 128x128 tile, BK=32, 4 waves (2x2), 4x4 16x16x32 MFMA frags per wave.
#define GLOAD16(gsrc, ldst)                                                     \
  __builtin_amdgcn_global_load_lds(                                             \
      (const __attribute__((address_space(1))) unsigned int*)(gsrc),            \
      (__attribute__((address_space(3))) unsigned int*)(ldst), 16, 0, 0)

__global__ __launch_bounds__(256) void gemm_gelu_kernel(
    const unsigned short* __restrict__ A,   // d bf16 [NPIX][1024]
    const unsigned short* __restrict__ Bw,  // conv_w bf16 [o][c]
    const float* __restrict__ bias,
    const float* __restrict__ x,
    float* __restrict__ out) {
  __shared__ unsigned short lA[128 * 32];
  __shared__ unsigned short lB[128 * 32];

  // XCD swizzle: 1568 blocks = 8 XCD * 196; n-inner so 8 n-tiles sharing an
  // A-panel run consecutively on the same XCD.
  int bid = blockIdx.x;
  int X = bid & 7, slot = bid >> 3;
  int j = X * 196 + slot;
  int mt = j >> 3, nt = j & 7;
  int p0 = mt * 128, n0 = nt * 128;

  int tid = threadIdx.x;
  int l = tid & 63, wid = tid >> 6;
  int wr = wid >> 1, wc = wid & 1;
  int lr = l & 15, lg = l >> 4;

  f32x4 acc[4][4];
#pragma unroll
  for (int m = 0; m < 4; ++m)
#pragma unroll
    for (int n = 0; n < 4; ++n) acc[m][n] = f32x4{0.f, 0.f, 0.f, 0.f};

  int arow = tid >> 2, acg = tid & 3;  // 4 threads per 64B row-slice
  const unsigned short* ag0 = A + (size_t)(p0 + arow) * CCH + acg * 8;
  const unsigned short* ag1 = ag0 + (size_t)64 * CCH;
  const unsigned short* bg0 = Bw + (size_t)(n0 + arow) * CCH + acg * 8;
  const unsigned short* bg1 = bg0 + (size_t)64 * CCH;
  unsigned short* la0 = lA + wid * 512;          // wave-uniform LDS bases
  unsigned short* la1 = lA + 2048 + wid * 512;
  unsigned short* lb0 = lB + wid * 512;
  unsigned short* lb1 = lB + 2048 + wid * 512;

  const unsigned short* lAf = lA + (wr * 64 + lr) * 32 + lg * 8;
  const unsigned short* lBf = lB + (wc * 64 + lr) * 32 + lg * 8;

  for (int kk = 0; kk < 32; ++kk) {
    __syncthreads();
    GLOAD16(ag0 + kk * 32, la0);
    GLOAD16(ag1 + kk * 32, la1);
    GLOAD16(bg0 + kk * 32, lb0);
    GLOAD16(bg1 + kk * 32, lb1);
    __syncthreads();
    short8 af[4], bf[4];
#pragma unroll
    for (int m = 0; m < 4; ++m) af[m] = *(const short8*)(lAf + m * 512);
#pragma unroll
    for (int n = 0; n < 4; ++n) bf[n] = *(const short8*)(lBf + n * 512);
#pragma unroll
    for (int m = 0; m < 4; ++m)
#pragma unroll
      for (int n = 0; n < 4; ++n)
        acc[m][n] = __builtin_amdgcn_mfma_f32_16x16x32_bf16(af[m], bf[n], acc[m][n], 0, 0, 0);
  }

  // epilogue: D col = lane&15 (=o), row = (lane>>4)*4 + reg (=pixel)
#pragma unroll
  for (int n = 0; n < 4; ++n) {
    int col = n0 + wc * 64 + n * 16 + lr;
    float bcol = bias[col];
#pragma unroll
    for (int m = 0; m < 4; ++m) {
      int prow = p0 + wr * 64 + m * 16 + lg * 4;
#pragma unroll
      for (int r = 0; r < 4; ++r) {
        int p = prow + r;
        int bt = p / 196, hw = p - bt * 196;
        size_t idx = (size_t)bt * BTSTR + (size_t)col * HWN + hw;
        float v = acc[m][n][r] + bcol;
        float ge = 0.5f * v * (1.0f + erff(v * 0.70710678118654752f));
        out[idx] = x[idx] + ge;
      }
    }
  }
}

// ---------------------------------------------------------------- launcher
extern "C" void kernel_launch(void* const* d_in, const int* in_sizes, int n_in,
                              void* d_out, int out_size, void* d_ws, size_t ws_size,
                              hipStream_t stream) {
  const float* x      = (const float*)d_in[0];
  const float* wfilt  = (const float*)d_in[1];
  const float* conv_w = (const float*)d_in[2];
  const float* conv_b = (const float*)d_in[3];
  // d_in[4] = n_segments (=8), baked into the kernels.
  char* ws = (char*)d_ws;
  unsigned short* dmat = (unsigned short*)(ws + WS_D);
  unsigned short* bw   = (unsigned short*)(ws + WS_BW);
  float2* tw           = (float2*)(ws + WS_TW);
  float* out           = (float*)d_out;

  init_tw_kernel<<<1, 512, 0, stream>>>(tw);
  wcast_kernel<<<1024, 256, 0, stream>>>(conv_w, bw);
  fft_filter_kernel<<<6272, 256, 0, stream>>>(x, wfilt, tw, dmat);
  gemm_gelu_kernel<<<1568, 256, 0, stream>>>(dmat, bw, conv_b, x, out);
}

// Round 2
// 249.847 us; speedup vs baseline: 1.2996x; 1.2996x over previous
//
#include <hip/hip_runtime.h>
#include <hip/hip_bf16.h>
#include <math.h>

typedef short short8 __attribute__((ext_vector_type(8)));
typedef float f32x4 __attribute__((ext_vector_type(4)));

// ---- problem dims (fixed by setup_inputs) ----
#define BTN   128            // b*t
#define HWN   196            // 14*14
#define CCH   1024
#define NPIX  (BTN * HWN)    // 25088 = 3136 * 8
#define BTSTR (CCH * HWN)    // 200704 floats per bt slab

// ---- workspace layout (bytes) ----
#define WS_D  0                      // d matrix bf16 [NPIX][1024]  = 51,380,224 B
#define WS_BW 51380224               // conv_w bf16 [1024][1024]    =  2,097,152 B

// ---- complex helpers ----
__device__ __forceinline__ float2 cadd(float2 a, float2 b) { return make_float2(a.x + b.x, a.y + b.y); }
__device__ __forceinline__ float2 csub(float2 a, float2 b) { return make_float2(a.x - b.x, a.y - b.y); }
__device__ __forceinline__ float2 cmulf(float2 a, float2 b) {
  return make_float2(a.x * b.x - a.y * b.y, a.x * b.y + a.y * b.x);
}
__device__ __forceinline__ float2 cmulc(float2 a, float2 b) {   // a * conj(b)
  return make_float2(a.x * b.x + a.y * b.y, a.y * b.x - a.x * b.y);
}
__device__ __forceinline__ float2 csqr(float2 a) {
  return make_float2(a.x * a.x - a.y * a.y, 2.f * a.x * a.y);
}
__device__ __forceinline__ float2 cneg(float2 a) { return make_float2(-a.x, -a.y); }
__device__ __forceinline__ unsigned short f2bf(float f) {   // RNE fp32->bf16
  unsigned u = __float_as_uint(f);
  unsigned r = (u + 0x7fffu + ((u >> 16) & 1u)) >> 16;
  return (unsigned short)r;
}

// ---------------------------------------------------------------- W -> bf16
__global__ void wcast_kernel(const float* __restrict__ w, unsigned short* __restrict__ o) {
  int i = (blockIdx.x * 256 + threadIdx.x) * 4;   // grid 1024 x 256 covers 1<<20
  float4 v = *(const float4*)(w + i);
  uint2 u;
  u.x = (unsigned)f2bf(v.x) | ((unsigned)f2bf(v.y) << 16);
  u.y = (unsigned)f2bf(v.z) | ((unsigned)f2bf(v.w) << 16);
  *(uint2*)(o + i) = u;
}

// ---------------------------------------------------------------- stage 1: FFT filter
// Block = 256 thr (4 waves), 8 pixels. Coalesced staging of x[*, c, hw] into
// LDS tile [8 px][1028], then each wave does 2 pixels' 512-pt FFTs fully in
// registers (8 float2/lane; in-lane stages for bits 8..6, shfl_xor for 5..0).
// Middle (real-spectrum unpack * filter * repack) runs in LDS (wave-private).
#define TS 1028   // tile row stride in floats: 1028 % 32 == 4 -> 2-way on stage writes

__global__ __launch_bounds__(256) void fft_filter_kernel(
    const float* __restrict__ x, const float* __restrict__ wfilt,
    unsigned short* __restrict__ dmat) {
  __shared__ float tile[8 * TS];
  __shared__ float2 tw10s[257];
  int tid = threadIdx.x;
  int l = tid & 63, w = tid >> 6;

  // twiddle table for the middle section: W_1024^f
  for (int i = tid; i < 257; i += 256) {
    float s, c;
    __sincosf(-6.283185307179586f * (float)i / 1024.0f, &s, &c);
    tw10s[i] = make_float2(c, s);
  }

  // XCD-chunked pixel mapping: consecutive-p blocks share an XCD (L2 line reuse)
  int blk = (blockIdx.x & 7) * 392 + (blockIdx.x >> 3);   // 3136 = 8 * 392
  int p_base = blk * 8;

  // ---- staging: thread t loads pixel (t&7), channels (t>>3) + 32*it ----
  {
    int px = tid & 7, ch = tid >> 3;
    int p = p_base + px;
    int bt = p / HWN, hw = p - bt * HWN;
    const float* src = x + (size_t)bt * BTSTR + hw;
    float* drow = tile + px * TS;
#pragma unroll
    for (int it = 0; it < 32; ++it) {
      int c = ch + 32 * it;
      drow[c] = src[(size_t)c * HWN];
    }
  }
  __syncthreads();

  // ---- per-lane register twiddles (pixel-independent) ----
  const float H = 0.70710678118654752f;
  float2 Wl;
  { float s, c; __sincosf(-6.283185307179586f * (float)l / 512.0f, &s, &c); Wl = make_float2(c, s); }
  float2 W2l = csqr(Wl), W4l = csqr(W2l);
  float2 W2li = make_float2(W2l.y, -W2l.x);                 // W2l * (-i)
  float2 T01 = cmulf(Wl, make_float2(H, -H));
  float2 T02 = make_float2(Wl.y, -Wl.x);                    // Wl * (-i)
  float2 T03 = cmulf(Wl, make_float2(-H, -H));
  float2 t3 = csqr(W4l); if (l & 32) t3 = cneg(t3);         // exp(-2pi i (l&31)/64)
  float2 t4 = csqr(t3);  if (l & 16) t4 = cneg(t4);
  float2 t5 = csqr(t4);  if (l & 8)  t5 = cneg(t5);
  float2 t6 = csqr(t5);  if (l & 4)  t6 = cneg(t6);
  float2 t7 = csqr(t6);  if (l & 2)  t7 = cneg(t7);

#pragma unroll 1
  for (int pp = 0; pp < 2; ++pp) {
    int px = w * 2 + pp;
    int p = p_base + px;
    int bt = p / HWN, hw = p - bt * HWN;
    float2* zrow = (float2*)(tile + px * TS);

    float2 zr[8];
#pragma unroll
    for (int r = 0; r < 8; ++r) zr[r] = zrow[l + 64 * r];

    // ---- forward DIF ----
    // st=0: pairs (r, r+4), tw = Wl * E8[r]
    {
      float2 T0[4] = {Wl, T01, T02, T03};
#pragma unroll
      for (int r = 0; r < 4; ++r) {
        float2 a = zr[r], b = zr[r + 4];
        zr[r] = cadd(a, b);
        zr[r + 4] = cmulf(csub(a, b), T0[r]);
      }
    }
    // st=1: pairs (r, r+2), lower r in {0,1,4,5}
#pragma unroll
    for (int h = 0; h < 2; ++h) {
      int b0 = h * 4;
      float2 a = zr[b0], b = zr[b0 + 2];
      zr[b0] = cadd(a, b); zr[b0 + 2] = cmulf(csub(a, b), W2l);
      a = zr[b0 + 1]; b = zr[b0 + 3];
      zr[b0 + 1] = cadd(a, b); zr[b0 + 3] = cmulf(csub(a, b), W2li);
    }
    // st=2: pairs (r, r+1), tw = W4l
#pragma unroll
    for (int r = 0; r < 8; r += 2) {
      float2 a = zr[r], b = zr[r + 1];
      zr[r] = cadd(a, b); zr[r + 1] = cmulf(csub(a, b), W4l);
    }
    // st=3..8: cross-lane, masks 32,16,8,4,2,1
    {
      float2 tws[6] = {t3, t4, t5, t6, t7, make_float2(1.f, 0.f)};
      int masks[6] = {32, 16, 8, 4, 2, 1};
#pragma unroll
      for (int s = 0; s < 6; ++s) {
        int m = masks[s];
        bool up = (l & m) != 0;
        float2 te = up ? tws[s] : make_float2(1.f, 0.f);
#pragma unroll
        for (int r = 0; r < 8; ++r) {
          float2 v = zr[r];
          float2 o = make_float2(__shfl_xor(v.x, m, 64), __shfl_xor(v.y, m, 64));
          float2 d = up ? csub(o, v) : cadd(v, o);
          zr[r] = cmulf(d, te);
        }
      }
    }

    // ---- middle: spill to LDS (wave-private), unpack*filter*repack ----
#pragma unroll
    for (int r = 0; r < 8; ++r) zrow[l + 64 * r] = zr[r];
    {
      float2* z = zrow;
      const float* wf = wfilt + (size_t)((bt & 7) * HWN + hw) * 1026;  // [513][2]
      const float sc = 1.0f / 512.0f;
#pragma unroll
      for (int i = 0; i < 4; ++i) {
        int f = 64 * i + l;
        if (f == 0) {
          float2 z0 = z[0];                       // Z[0]
          float X0 = z0.x + z0.y, X512 = z0.x - z0.y;
          float Y0 = X0 * wf[0] * sc;             // irfft ignores Im at bin 0
          float Y512 = X512 * wf[1024] * sc;      // and bin 512
          z[0] = make_float2(0.5f * (Y0 + Y512), 0.5f * (Y0 - Y512));
          float2 z2 = z[1];                       // bitrev(256)=1 -> Z[256]
          float2 X256 = make_float2(z2.x, -z2.y); // conj(Z256)
          float2 Y = cmulf(X256, make_float2(wf[512], wf[513]));
          z[1] = make_float2(Y.x * sc, -Y.y * sc);
        } else {
          int g = 512 - f;
          int pf = (int)(__brev((unsigned)f) >> 23);
          int pg = (int)(__brev((unsigned)g) >> 23);
          float2 Zf = z[pf], Zg = z[pg];
          float2 A = make_float2(0.5f * (Zf.x + Zg.x), 0.5f * (Zf.y - Zg.y));
          float2 B = make_float2(0.5f * (Zf.y + Zg.y), -0.5f * (Zf.x - Zg.x));
          float2 Wf = tw10s[f];
          float2 WB = cmulf(Wf, B);
          float2 Xf = make_float2(A.x + WB.x, A.y + WB.y);       // X[f]
          float2 Xg = make_float2(A.x - WB.x, -(A.y - WB.y));    // X[512-f] = conj(A-WB)
          float2 Yf = cmulf(Xf, make_float2(wf[2 * f], wf[2 * f + 1]));
          float2 Yg = cmulf(Xg, make_float2(wf[2 * g], wf[2 * g + 1]));
          Yf.x *= sc; Yf.y *= sc; Yg.x *= sc; Yg.y *= sc;
          float2 Ap = make_float2(0.5f * (Yf.x + Yg.x), 0.5f * (Yf.y - Yg.y));
          float2 T  = make_float2(0.5f * (Yf.x - Yg.x), 0.5f * (Yf.y + Yg.y));
          float2 Bp = cmulf(make_float2(Wf.x, -Wf.y), T);
          z[pf] = make_float2(Ap.x - Bp.y, Ap.y + Bp.x);         // Z'[f] = A' + iB'
          z[pg] = make_float2(Ap.x + Bp.y, Bp.x - Ap.y);         // Z'[g] = conj(A'-iB')
        }
      }
    }
#pragma unroll
    for (int r = 0; r < 8; ++r) zr[r] = zrow[l + 64 * r];

    // ---- inverse DIT (conj twiddles, reversed stage order) ----
    {
      float2 tws[6] = {make_float2(1.f, 0.f), t7, t6, t5, t4, t3};
      int masks[6] = {1, 2, 4, 8, 16, 32};
#pragma unroll
      for (int s = 0; s < 6; ++s) {
        int m = masks[s];
        bool up = (l & m) != 0;
        float2 te = up ? make_float2(tws[s].x, -tws[s].y) : make_float2(1.f, 0.f);
#pragma unroll
        for (int r = 0; r < 8; ++r) {
          float2 v = cmulf(zr[r], te);
          float2 o = make_float2(__shfl_xor(v.x, m, 64), __shfl_xor(v.y, m, 64));
          zr[r] = up ? csub(o, v) : cadd(v, o);
        }
      }
    }
    // st=2 inverse
#pragma unroll
    for (int r = 0; r < 8; r += 2) {
      float2 v = cmulc(zr[r + 1], W4l);
      float2 a = zr[r];
      zr[r] = cadd(a, v); zr[r + 1] = csub(a, v);
    }
    // st=1 inverse
#pragma unroll
    for (int h = 0; h < 2; ++h) {
      int b0 = h * 4;
      float2 v = cmulc(zr[b0 + 2], W2l);
      float2 a = zr[b0];
      zr[b0] = cadd(a, v); zr[b0 + 2] = csub(a, v);
      v = cmulc(zr[b0 + 3], W2li);
      a = zr[b0 + 1];
      zr[b0 + 1] = cadd(a, v); zr[b0 + 3] = csub(a, v);
    }
    // st=0 inverse
    {
      float2 T0[4] = {Wl, T01, T02, T03};
#pragma unroll
      for (int r = 0; r < 4; ++r) {
        float2 v = cmulc(zr[r + 4], T0[r]);
        float2 a = zr[r];
        zr[r] = cadd(a, v); zr[r + 4] = csub(a, v);
      }
    }

    // ---- pack bf16, store d row coalesced ----
    unsigned* dst = (unsigned*)(dmat + (size_t)p * CCH);
#pragma unroll
    for (int r = 0; r < 8; ++r) {
      float2 v = zr[r];
      dst[l + 64 * r] = (unsigned)f2bf(v.x) | ((unsigned)f2bf(v.y) << 16);
    }
  }
}

// ---------------------------------------------------------------- stage 2: GEMM + GELU + residual
// e[p][o] = sum_c d[p][c] * W[o][c] + b[o]; out = x + gelu(e)
// 128x128 tile, BK=32, 4 waves (2x2), 4x4 16x16x32 MFMA frags per wave.
// Operand order: mfma(W-frag, d-frag) -> D rows = channels, cols = pixels
// -> stores/x-loads coalesced along hw.
#define GLOAD16(gsrc, ldst)                                                     \
  __builtin_amdgcn_global_load_lds(                                             \
      (const __attribute__((address_space(1))) unsigned int*)(gsrc),            \
      (__attribute__((address_space(3))) unsigned int*)(ldst), 16, 0, 0)

__global__ __launch_bounds__(256) void gemm_gelu_kernel(
    const unsigned short* __restrict__ A,   // d bf16 [NPIX][1024]
    const unsigned short* __restrict__ Bw,  // conv_w bf16 [o][c]
    const float* __restrict__ bias,
    const float* __restrict__ x,
    float* __restrict__ out) {
  __shared__ unsigned short lA[128 * 32];
  __shared__ unsigned short lB[128 * 32];

  // XCD swizzle: 1568 blocks = 8 XCD * 196; n-inner so 8 n-tiles sharing an
  // A-panel run consecutively on the same XCD.
  int bid = blockIdx.x;
  int X = bid & 7, slot = bid >> 3;
  int j = X * 196 + slot;
  int mt = j >> 3, nt = j & 7;
  int p0 = mt * 128, n0 = nt * 128;

  int tid = threadIdx.x;
  int l = tid & 63, wid = tid >> 6;
  int wr = wid >> 1, wc = wid & 1;
  int lr = l & 15, lg = l >> 4;

  f32x4 acc[4][4];   // [channel frag][pixel frag]
#pragma unroll
  for (int i = 0; i < 4; ++i)
#pragma unroll
    for (int jj = 0; jj < 4; ++jj) acc[i][jj] = f32x4{0.f, 0.f, 0.f, 0.f};

  int arow = tid >> 2, acg = tid & 3;  // 4 threads per 64B row-slice
  const unsigned short* ag0 = A + (size_t)(p0 + arow) * CCH + acg * 8;
  const unsigned short* ag1 = ag0 + (size_t)64 * CCH;
  const unsigned short* bg0 = Bw + (size_t)(n0 + arow) * CCH + acg * 8;
  const unsigned short* bg1 = bg0 + (size_t)64 * CCH;
  unsigned short* la0 = lA + wid * 512;          // wave-uniform LDS bases
  unsigned short* la1 = lA + 2048 + wid * 512;
  unsigned short* lb0 = lB + wid * 512;
  unsigned short* lb1 = lB + 2048 + wid * 512;

  const unsigned short* lAf = lA + (wr * 64 + lr) * 32 + lg * 8;
  const unsigned short* lBf = lB + (wc * 64 + lr) * 32 + lg * 8;

  for (int kk = 0; kk < 32; ++kk) {
    __syncthreads();
    GLOAD16(ag0 + kk * 32, la0);
    GLOAD16(ag1 + kk * 32, la1);
    GLOAD16(bg0 + kk * 32, lb0);
    GLOAD16(bg1 + kk * 32, lb1);
    __syncthreads();
    short8 af[4], bf[4];
#pragma unroll
    for (int m = 0; m < 4; ++m) af[m] = *(const short8*)(lAf + m * 512);
#pragma unroll
    for (int n = 0; n < 4; ++n) bf[n] = *(const short8*)(lBf + n * 512);
#pragma unroll
    for (int i = 0; i < 4; ++i)       // channel frags (W rows as M)
#pragma unroll
      for (int jj = 0; jj < 4; ++jj)  // pixel frags (d rows as N)
        acc[i][jj] = __builtin_amdgcn_mfma_f32_16x16x32_bf16(bf[i], af[jj], acc[i][jj], 0, 0, 0);
  }

  // epilogue: D row = (lane>>4)*4 + reg (=channel), col = lane&15 (=pixel)
#pragma unroll
  for (int i = 0; i < 4; ++i) {
#pragma unroll
    for (int jj = 0; jj < 4; ++jj) {
      int p = p0 + wr * 64 + jj * 16 + lr;
      int bt = p / HWN, hw = p - bt * HWN;
#pragma unroll
      for (int r = 0; r < 4; ++r) {
        int ch = n0 + wc * 64 + i * 16 + lg * 4 + r;
        size_t idx = (size_t)bt * BTSTR + (size_t)ch * HWN + hw;
        float v = acc[i][jj][r] + bias[ch];
        float ge = 0.5f * v * (1.0f + erff(v * 0.70710678118654752f));
        out[idx] = x[idx] + ge;
      }
    }
  }
}

// ---------------------------------------------------------------- launcher
extern "C" void kernel_launch(void* const* d_in, const int* in_sizes, int n_in,
                              void* d_out, int out_size, void* d_ws, size_t ws_size,
                              hipStream_t stream) {
  const float* x      = (const float*)d_in[0];
  const float* wfilt  = (const float*)d_in[1];
  const float* conv_w = (const float*)d_in[2];
  const float* conv_b = (const float*)d_in[3];
  // d_in[4] = n_segments (=8), baked into the kernels.
  char* ws = (char*)d_ws;
  unsigned short* dmat = (unsigned short*)(ws + WS_D);
  unsigned short* bw   = (unsigned short*)(ws + WS_BW);
  float* out           = (float*)d_out;

  wcast_kernel<<<1024, 256, 0, stream>>>(conv_w, bw);
  fft_filter_kernel<<<3136, 256, 0, stream>>>(x, wfilt, dmat);
  gemm_gelu_kernel<<<1568, 256, 0, stream>>>(dmat, bw, conv_b, x, out);
}

// Round 3
// 226.629 us; speedup vs baseline: 1.4328x; 1.1024x over previous
//
#include <hip/hip_runtime.h>
#include <hip/hip_bf16.h>
#include <math.h>

typedef short short8 __attribute__((ext_vector_type(8)));
typedef float f32x4 __attribute__((ext_vector_type(4)));

// ---- problem dims (fixed by setup_inputs) ----
#define BTN   128            // b*t
#define HWN   196            // 14*14
#define CCH   1024
#define NPIX  (BTN * HWN)    // 25088 = 3136 * 8
#define BTSTR (CCH * HWN)    // 200704 floats per bt slab

// ---- workspace layout (bytes) ----
#define WS_D  0                      // d matrix bf16 [NPIX][1024]  = 51,380,224 B
#define WS_BW 51380224               // conv_w bf16 [1024][1024]    =  2,097,152 B

// ---- complex helpers ----
__device__ __forceinline__ float2 cadd(float2 a, float2 b) { return make_float2(a.x + b.x, a.y + b.y); }
__device__ __forceinline__ float2 csub(float2 a, float2 b) { return make_float2(a.x - b.x, a.y - b.y); }
__device__ __forceinline__ float2 cmulf(float2 a, float2 b) {
  return make_float2(a.x * b.x - a.y * b.y, a.x * b.y + a.y * b.x);
}
__device__ __forceinline__ float2 cmulc(float2 a, float2 b) {   // a * conj(b)
  return make_float2(a.x * b.x + a.y * b.y, a.y * b.x - a.x * b.y);
}
__device__ __forceinline__ float2 csqr(float2 a) {
  return make_float2(a.x * a.x - a.y * a.y, 2.f * a.x * a.y);
}
__device__ __forceinline__ float2 cneg(float2 a) { return make_float2(-a.x, -a.y); }
__device__ __forceinline__ unsigned short f2bf(float f) {   // RNE fp32->bf16
  unsigned u = __float_as_uint(f);
  unsigned r = (u + 0x7fffu + ((u >> 16) & 1u)) >> 16;
  return (unsigned short)r;
}

// ---------------------------------------------------------------- W -> bf16
__global__ void wcast_kernel(const float* __restrict__ w, unsigned short* __restrict__ o) {
  int i = (blockIdx.x * 256 + threadIdx.x) * 4;   // grid 1024 x 256 covers 1<<20
  float4 v = *(const float4*)(w + i);
  uint2 u;
  u.x = (unsigned)f2bf(v.x) | ((unsigned)f2bf(v.y) << 16);
  u.y = (unsigned)f2bf(v.z) | ((unsigned)f2bf(v.w) << 16);
  *(uint2*)(o + i) = u;
}

// ---------------------------------------------------------------- stage 1: FFT filter
// Block = 256 thr (4 waves), 8 pixels. float4 staging of x[*, c, hw] into LDS
// tile [8 px][1028] (4 px per load along hw; 196%4==0 so groups never cross a
// bt row), then each wave does 2 pixels' 512-pt FFTs in registers (8
// float2/lane; in-lane stages bits 8..6, shfl_xor bits 5..0). Middle
// (real-spectrum unpack * filter * repack) runs in LDS (wave-private).
#define TS 1028   // tile row stride in floats: 1028 % 32 == 4 -> 2-way on stage writes

__global__ __launch_bounds__(256) void fft_filter_kernel(
    const float* __restrict__ x, const float* __restrict__ wfilt,
    unsigned short* __restrict__ dmat) {
  __shared__ float tile[8 * TS];
  __shared__ float2 tw10s[257];
  int tid = threadIdx.x;
  int l = tid & 63, w = tid >> 6;

  // twiddle table for the middle section: W_1024^f
  for (int i = tid; i < 257; i += 256) {
    float s, c;
    __sincosf(-6.283185307179586f * (float)i / 1024.0f, &s, &c);
    tw10s[i] = make_float2(c, s);
  }

  // XCD-chunked pixel mapping: consecutive-p blocks share an XCD (L2 line reuse)
  int blk = (blockIdx.x & 7) * 392 + (blockIdx.x >> 3);   // 3136 = 8 * 392
  int p_base = blk * 8;

  // ---- staging: thread t loads float4 (4 px) of group (t&1), channel (t>>1)+128*it ----
  {
    int g = tid & 1, chb = tid >> 1;
    int p = p_base + 4 * g;
    int bt = p / HWN, hw = p - bt * HWN;          // hw%4==0, group stays in row
    const float* src = x + (size_t)bt * BTSTR + hw;
    float* rowb = tile + (4 * g) * TS;
#pragma unroll
    for (int it = 0; it < 8; ++it) {
      int c = chb + 128 * it;
      float4 v = *(const float4*)(src + (size_t)c * HWN);
      float* b = rowb + c;
      b[0 * TS] = v.x; b[1 * TS] = v.y; b[2 * TS] = v.z; b[3 * TS] = v.w;
    }
  }
  __syncthreads();

  // ---- per-lane register twiddles (pixel-independent) ----
  const float H = 0.70710678118654752f;
  float2 Wl;
  { float s, c; __sincosf(-6.283185307179586f * (float)l / 512.0f, &s, &c); Wl = make_float2(c, s); }
  float2 W2l = csqr(Wl), W4l = csqr(W2l);
  float2 W2li = make_float2(W2l.y, -W2l.x);                 // W2l * (-i)
  float2 T01 = cmulf(Wl, make_float2(H, -H));
  float2 T02 = make_float2(Wl.y, -Wl.x);                    // Wl * (-i)
  float2 T03 = cmulf(Wl, make_float2(-H, -H));
  float2 t3 = csqr(W4l); if (l & 32) t3 = cneg(t3);         // exp(-2pi i (l&31)/64)
  float2 t4 = csqr(t3);  if (l & 16) t4 = cneg(t4);
  float2 t5 = csqr(t4);  if (l & 8)  t5 = cneg(t5);
  float2 t6 = csqr(t5);  if (l & 4)  t6 = cneg(t6);
  float2 t7 = csqr(t6);  if (l & 2)  t7 = cneg(t7);

#pragma unroll 1
  for (int pp = 0; pp < 2; ++pp) {
    int px = w * 2 + pp;
    int p = p_base + px;
    int bt = p / HWN, hw = p - bt * HWN;
    float2* zrow = (float2*)(tile + px * TS);

    float2 zr[8];
#pragma unroll
    for (int r = 0; r < 8; ++r) zr[r] = zrow[l + 64 * r];

    // ---- forward DIF ----
    {
      float2 T0[4] = {Wl, T01, T02, T03};
#pragma unroll
      for (int r = 0; r < 4; ++r) {
        float2 a = zr[r], b = zr[r + 4];
        zr[r] = cadd(a, b);
        zr[r + 4] = cmulf(csub(a, b), T0[r]);
      }
    }
#pragma unroll
    for (int h = 0; h < 2; ++h) {
      int b0 = h * 4;
      float2 a = zr[b0], b = zr[b0 + 2];
      zr[b0] = cadd(a, b); zr[b0 + 2] = cmulf(csub(a, b), W2l);
      a = zr[b0 + 1]; b = zr[b0 + 3];
      zr[b0 + 1] = cadd(a, b); zr[b0 + 3] = cmulf(csub(a, b), W2li);
    }
#pragma unroll
    for (int r = 0; r < 8; r += 2) {
      float2 a = zr[r], b = zr[r + 1];
      zr[r] = cadd(a, b); zr[r + 1] = cmulf(csub(a, b), W4l);
    }
    // st=3..8: cross-lane, masks 32,16,8,4,2,1
    {
      float2 tws[6] = {t3, t4, t5, t6, t7, make_float2(1.f, 0.f)};
      int masks[6] = {32, 16, 8, 4, 2, 1};
#pragma unroll
      for (int s = 0; s < 6; ++s) {
        int m = masks[s];
        bool up = (l & m) != 0;
        float2 te = up ? tws[s] : make_float2(1.f, 0.f);
#pragma unroll
        for (int r = 0; r < 8; ++r) {
          float2 v = zr[r];
          float2 o = make_float2(__shfl_xor(v.x, m, 64), __shfl_xor(v.y, m, 64));
          float2 d = up ? csub(o, v) : cadd(v, o);
          zr[r] = cmulf(d, te);
        }
      }
    }

    // ---- middle: spill to LDS (wave-private), unpack*filter*repack ----
#pragma unroll
    for (int r = 0; r < 8; ++r) zrow[l + 64 * r] = zr[r];
    {
      float2* z = zrow;
      const float* wf = wfilt + (size_t)((bt & 7) * HWN + hw) * 1026;  // [513][2]
      const float sc = 1.0f / 512.0f;
#pragma unroll
      for (int i = 0; i < 4; ++i) {
        int f = 64 * i + l;
        if (f == 0) {
          float2 z0 = z[0];                       // Z[0]
          float X0 = z0.x + z0.y, X512 = z0.x - z0.y;
          float Y0 = X0 * wf[0] * sc;             // irfft ignores Im at bin 0
          float Y512 = X512 * wf[1024] * sc;      // and bin 512
          z[0] = make_float2(0.5f * (Y0 + Y512), 0.5f * (Y0 - Y512));
          float2 z2 = z[1];                       // bitrev(256)=1 -> Z[256]
          float2 X256 = make_float2(z2.x, -z2.y); // conj(Z256)
          float2 Y = cmulf(X256, make_float2(wf[512], wf[513]));
          z[1] = make_float2(Y.x * sc, -Y.y * sc);
        } else {
          int g = 512 - f;
          int pf = (int)(__brev((unsigned)f) >> 23);
          int pg = (int)(__brev((unsigned)g) >> 23);
          float2 Zf = z[pf], Zg = z[pg];
          float2 A = make_float2(0.5f * (Zf.x + Zg.x), 0.5f * (Zf.y - Zg.y));
          float2 B = make_float2(0.5f * (Zf.y + Zg.y), -0.5f * (Zf.x - Zg.x));
          float2 Wf = tw10s[f];
          float2 WB = cmulf(Wf, B);
          float2 Xf = make_float2(A.x + WB.x, A.y + WB.y);       // X[f]
          float2 Xg = make_float2(A.x - WB.x, -(A.y - WB.y));    // X[512-f] = conj(A-WB)
          float2 Yf = cmulf(Xf, make_float2(wf[2 * f], wf[2 * f + 1]));
          float2 Yg = cmulf(Xg, make_float2(wf[2 * g], wf[2 * g + 1]));
          Yf.x *= sc; Yf.y *= sc; Yg.x *= sc; Yg.y *= sc;
          float2 Ap = make_float2(0.5f * (Yf.x + Yg.x), 0.5f * (Yf.y - Yg.y));
          float2 T  = make_float2(0.5f * (Yf.x - Yg.x), 0.5f * (Yf.y + Yg.y));
          float2 Bp = cmulf(make_float2(Wf.x, -Wf.y), T);
          z[pf] = make_float2(Ap.x - Bp.y, Ap.y + Bp.x);         // Z'[f] = A' + iB'
          z[pg] = make_float2(Ap.x + Bp.y, Bp.x - Ap.y);         // Z'[g] = conj(A'-iB')
        }
      }
    }
#pragma unroll
    for (int r = 0; r < 8; ++r) zr[r] = zrow[l + 64 * r];

    // ---- inverse DIT (conj twiddles, reversed stage order) ----
    {
      float2 tws[6] = {make_float2(1.f, 0.f), t7, t6, t5, t4, t3};
      int masks[6] = {1, 2, 4, 8, 16, 32};
#pragma unroll
      for (int s = 0; s < 6; ++s) {
        int m = masks[s];
        bool up = (l & m) != 0;
        float2 te = up ? make_float2(tws[s].x, -tws[s].y) : make_float2(1.f, 0.f);
#pragma unroll
        for (int r = 0; r < 8; ++r) {
          float2 v = cmulf(zr[r], te);
          float2 o = make_float2(__shfl_xor(v.x, m, 64), __shfl_xor(v.y, m, 64));
          zr[r] = up ? csub(o, v) : cadd(v, o);
        }
      }
    }
#pragma unroll
    for (int r = 0; r < 8; r += 2) {
      float2 v = cmulc(zr[r + 1], W4l);
      float2 a = zr[r];
      zr[r] = cadd(a, v); zr[r + 1] = csub(a, v);
    }
#pragma unroll
    for (int h = 0; h < 2; ++h) {
      int b0 = h * 4;
      float2 v = cmulc(zr[b0 + 2], W2l);
      float2 a = zr[b0];
      zr[b0] = cadd(a, v); zr[b0 + 2] = csub(a, v);
      v = cmulc(zr[b0 + 3], W2li);
      a = zr[b0 + 1];
      zr[b0 + 1] = cadd(a, v); zr[b0 + 3] = csub(a, v);
    }
    {
      float2 T0[4] = {Wl, T01, T02, T03};
#pragma unroll
      for (int r = 0; r < 4; ++r) {
        float2 v = cmulc(zr[r + 4], T0[r]);
        float2 a = zr[r];
        zr[r] = cadd(a, v); zr[r + 4] = csub(a, v);
      }
    }

    // ---- pack bf16, store d row coalesced ----
    unsigned* dst = (unsigned*)(dmat + (size_t)p * CCH);
#pragma unroll
    for (int r = 0; r < 8; ++r) {
      float2 v = zr[r];
      dst[l + 64 * r] = (unsigned)f2bf(v.x) | ((unsigned)f2bf(v.y) << 16);
    }
  }
}

// ---------------------------------------------------------------- stage 2: GEMM + GELU + residual
// e[p][o] = sum_c d[p][c] * W[o][c] + b[o]; out = x + gelu(e)
// 128(M=pixels) x 256(N=channels) tile, BK=32, 8 waves (2Mx4N), double-buffered
// LDS, 2-phase pipeline: stage k+1 before compute k, one barrier per step.
// mfma(W-frag, d-frag) -> D rows = channels, cols = pixels (coalesced stores).
#define GLOAD16(gsrc, ldst)                                                     \
  __builtin_amdgcn_global_load_lds(                                             \
      (const __attribute__((address_space(1))) unsigned int*)(gsrc),            \
      (__attribute__((address_space(3))) unsigned int*)(ldst), 16, 0, 0)

__global__ __launch_bounds__(512) void gemm_gelu_kernel(
    const unsigned short* __restrict__ A,   // d bf16 [NPIX][1024]
    const unsigned short* __restrict__ Bw,  // conv_w bf16 [o][c]
    const float* __restrict__ bias,
    const float* __restrict__ x,
    float* __restrict__ out) {
  __shared__ unsigned short lA[2 * 128 * 32];   // 16 KB
  __shared__ unsigned short lB[2 * 256 * 32];   // 32 KB

  // XCD swizzle: 784 blocks = 8 XCD * 98; n-inner so the 4 n-tiles sharing an
  // A-panel run consecutively on the same XCD.
  int bid = blockIdx.x;
  int X = bid & 7, slot = bid >> 3;
  int j = X * 98 + slot;
  int mt = j >> 2, nt = j & 3;
  int p0 = mt * 128, n0 = nt * 256;

  int tid = threadIdx.x;
  int l = tid & 63, wid = tid >> 6;
  int wr = wid >> 2, wc = wid & 3;   // wave tile: rows p0+wr*64, cols n0+wc*64
  int lr = l & 15, lg = l >> 4;

  f32x4 acc[4][4];   // [channel frag][pixel frag]
#pragma unroll
  for (int i = 0; i < 4; ++i)
#pragma unroll
    for (int jj = 0; jj < 4; ++jj) acc[i][jj] = f32x4{0.f, 0.f, 0.f, 0.f};

  int arow = tid >> 2, acg = tid & 3;  // 512 threads = 128 rows x 4 16B-slices
  const unsigned short* ag  = A  + (size_t)(p0 + arow) * CCH + acg * 8;
  const unsigned short* bg0 = Bw + (size_t)(n0 + arow) * CCH + acg * 8;
  const unsigned short* bg1 = bg0 + (size_t)128 * CCH;
  unsigned short* laW = lA + wid * 512;   // wave-uniform LDS bases (lane*16B HW-added)
  unsigned short* lbW = lB + wid * 512;

#define STAGE(buf, kk)                                                          \
  do {                                                                          \
    GLOAD16(ag  + (kk) * 32, laW + (buf) * 4096);                               \
    GLOAD16(bg0 + (kk) * 32, lbW + (buf) * 8192);                               \
    GLOAD16(bg1 + (kk) * 32, lbW + (buf) * 8192 + 4096);                        \
  } while (0)

  STAGE(0, 0);
  __syncthreads();   // drains vmcnt(0)

  int cur = 0;
  for (int kk = 0; kk < 32; ++kk) {
    if (kk < 31) STAGE(cur ^ 1, kk + 1);          // prefetch overlaps compute
    const unsigned short* lAf = lA + cur * 4096 + (wr * 64 + lr) * 32 + lg * 8;
    const unsigned short* lBf = lB + cur * 8192 + (wc * 64 + lr) * 32 + lg * 8;
    short8 af[4], bf[4];
#pragma unroll
    for (int m = 0; m < 4; ++m) af[m] = *(const short8*)(lAf + m * 512);
#pragma unroll
    for (int n = 0; n < 4; ++n) bf[n] = *(const short8*)(lBf + n * 512);
#pragma unroll
    for (int i = 0; i < 4; ++i)       // channel frags (W rows as M)
#pragma unroll
      for (int jj = 0; jj < 4; ++jj)  // pixel frags (d rows as N)
        acc[i][jj] = __builtin_amdgcn_mfma_f32_16x16x32_bf16(bf[i], af[jj], acc[i][jj], 0, 0, 0);
    __syncthreads();   // drains this step's prefetch; frees buf cur for re-stage
    cur ^= 1;
  }
#undef STAGE

  // epilogue: D row = (lane>>4)*4 + reg (=channel), col = lane&15 (=pixel)
#pragma unroll
  for (int i = 0; i < 4; ++i) {
#pragma unroll
    for (int jj = 0; jj < 4; ++jj) {
      int p = p0 + wr * 64 + jj * 16 + lr;
      int bt = p / HWN, hw = p - bt * HWN;
#pragma unroll
      for (int r = 0; r < 4; ++r) {
        int ch = n0 + wc * 64 + i * 16 + lg * 4 + r;
        size_t idx = (size_t)bt * BTSTR + (size_t)ch * HWN + hw;
        float v = acc[i][jj][r] + bias[ch];
        float ge = 0.5f * v * (1.0f + erff(v * 0.70710678118654752f));
        out[idx] = x[idx] + ge;
      }
    }
  }
}

// ---------------------------------------------------------------- launcher
extern "C" void kernel_launch(void* const* d_in, const int* in_sizes, int n_in,
                              void* d_out, int out_size, void* d_ws, size_t ws_size,
                              hipStream_t stream) {
  const float* x      = (const float*)d_in[0];
  const float* wfilt  = (const float*)d_in[1];
  const float* conv_w = (const float*)d_in[2];
  const float* conv_b = (const float*)d_in[3];
  // d_in[4] = n_segments (=8), baked into the kernels.
  char* ws = (char*)d_ws;
  unsigned short* dmat = (unsigned short*)(ws + WS_D);
  unsigned short* bw   = (unsigned short*)(ws + WS_BW);
  float* out           = (float*)d_out;

  wcast_kernel<<<1024, 256, 0, stream>>>(conv_w, bw);
  fft_filter_kernel<<<3136, 256, 0, stream>>>(x, wfilt, dmat);
  gemm_gelu_kernel<<<784, 512, 0, stream>>>(dmat, bw, conv_b, x, out);
}